// Round 11
// baseline (790.401 us; speedup 1.0000x reference)
//
#include <hip/hip_runtime.h>

#define NN 50000
#define CAP 32          // per-node bin capacity; overflow handled correctly
#define OVF_CAP 4096
#define NB 256          // coarse buckets over task space [0, 2*NN)
#define BKW 391         // tasks per bucket (391*256 = 100096 >= 100000)
#define BCAP 8192       // per-bucket entry capacity (mean 6252, std ~78)
#define QD 32           // phase-A LDS queue depth (cell mean ~12)

__device__ __forceinline__ unsigned short f2bf(float f) {
    unsigned u = __float_as_uint(f);
    u += 0x7fffu + ((u >> 16) & 1u);           // round-to-nearest-even
    return (unsigned short)(u >> 16);
}
__device__ __forceinline__ float bf2f(unsigned short u) {
    return __uint_as_float(((unsigned)u) << 16);
}

// fp32 -> bf16 row copy (n4 = count of float4s)
__global__ __launch_bounds__(256) void to_bf16(
    const float* __restrict__ in, unsigned short* __restrict__ out, int n4)
{
    int stride = gridDim.x * blockDim.x;
    for (int i = blockIdx.x * blockDim.x + threadIdx.x; i < n4; i += stride) {
        float4 v = ((const float4*)in)[i];
        ushort4 o;
        o.x = f2bf(v.x); o.y = f2bf(v.y); o.z = f2bf(v.z); o.w = f2bf(v.w);
        ((ushort4*)out)[i] = o;
    }
}

// ---- Phase A: multisplit edges into 256 coarse buckets via LDS queues ----
// R3-R10: scattered 2-4B stores/atomics plateau at ~1.25 TB/s with ~10x write
// amplification. R9 proved LDS staging fixes WRITE (6.6MB) but serialized on
// 64 blocks. This phase keeps full-chip parallelism: per-block LDS queues,
// end-of-block coalesced flush (one atomic per (block,bucket)).
// Entry = (src << 9) | (task - bucket*BKW)   [src < 2^16, local < 391 < 512]
__global__ __launch_bounds__(256) void bucket_scatter(
    const int* __restrict__ ei0, int E0,
    const int* __restrict__ ei1, int E1,
    unsigned int* __restrict__ bbuf, int* __restrict__ bcnt)
{
    __shared__ unsigned int q[NB][QD];
    __shared__ int qc[NB];
    int tid = threadIdx.x;
    for (int i = tid; i < NB; i += 256) qc[i] = 0;
    __syncthreads();

    int total = E0 + E1;
    int stride = gridDim.x * 256;
    for (int t = blockIdx.x * 256 + tid; t < total; t += stride) {
        int src, task;
        if (t < E0) { src = ei0[t]; task = ei0[E0 + t]; }
        else        { int u = t - E0; src = ei1[u]; task = NN + ei1[E1 + u]; }
        int b = task / BKW;
        unsigned e = ((unsigned)src << 9) | (unsigned)(task - b * BKW);
        int r = atomicAdd(&qc[b], 1);
        if (r < QD) {
            q[b][r] = e;
        } else {                                  // rare cell overflow: direct append
            int g = atomicAdd(&bcnt[b], 1);
            if (g < BCAP) bbuf[(size_t)b * BCAP + g] = e;
        }
    }
    __syncthreads();

    int lane = tid & 63;
    int wv = tid >> 6;
    for (int b = wv; b < NB; b += 4) {
        int c = min(qc[b], QD);
        int base = 0;
        if (lane == 0 && c > 0) base = atomicAdd(&bcnt[b], c);
        base = __shfl(base, 0);
        if (lane < c) {
            int g = base + lane;
            if (g < BCAP) bbuf[(size_t)b * BCAP + g] = q[b][lane];
        }
    }
}

// ---- Phase B: per-bucket LDS binning, fully coalesced writeout ----
// Each block reads ONLY its bucket's ~6.3k entries (25KB) — no full-list
// rescan (R9's failure mode). Writes bins+deg for its 391 tasks coalesced.
__global__ __launch_bounds__(1024, 1) void bin_build(
    const unsigned int* __restrict__ bbuf, const int* __restrict__ bcnt,
    int* __restrict__ deg, unsigned short* __restrict__ bins,
    int2* __restrict__ ovf, int* __restrict__ ovf_cnt)
{
    __shared__ unsigned short sbins[BKW * CAP];   // 25,024 B
    __shared__ unsigned int   sdeg[BKW];          // 1,564 B

    int b = blockIdx.x;
    int tid = threadIdx.x;
    int base_task = b * BKW;
    int n_tasks = min(BKW, 2 * NN - base_task);

    for (int i = tid; i < BKW; i += 1024) sdeg[i] = 0;
    __syncthreads();

    int cnt = min(bcnt[b], BCAP);
    for (int i = tid; i < cnt; i += 1024) {
        unsigned e = bbuf[(size_t)b * BCAP + i];
        int local = (int)(e & 511u);
        int src = (int)(e >> 9);
        unsigned r = atomicAdd(&sdeg[local], 1u);
        if (r < CAP) {
            sbins[local * CAP + r] = (unsigned short)src;
        } else {
            int o = atomicAdd(ovf_cnt, 1);
            if (o < OVF_CAP) ovf[o] = make_int2(base_task + local, src);
        }
    }
    __syncthreads();

    unsigned int* gb = (unsigned int*)(bins + (size_t)base_task * CAP);
    const unsigned int* sb = (const unsigned int*)sbins;
    int nwords = n_tasks * (CAP / 2);
    for (int i = tid; i < nwords; i += 1024) gb[i] = sb[i];
    for (int i = tid; i < n_tasks; i += 1024) deg[base_task + i] = (int)sdeg[i];
}

// One (rel,node) task per wave; paired gathers: lane loads a uint (2 bf16
// feats), low half-wave covers src 2q, high half src 2q+1 -> 2 rows per
// gather instruction at 4B/lane. 4 chains of ILP. (R9: halved agg time.)
__global__ __launch_bounds__(256) void aggregate(
    const unsigned short* __restrict__ bins, const int* __restrict__ deg,
    const unsigned short* __restrict__ hb, float* __restrict__ agg)
{
    int lane = threadIdx.x & 63;
    int half = lane >> 5;
    int p = lane & 31;                 // feature-pair index
    int wid = (blockIdx.x * blockDim.x + threadIdx.x) >> 6;
    int nwaves = (gridDim.x * blockDim.x) >> 6;
    const unsigned int* hb32 = (const unsigned int*)hb;

    for (int task = wid; task < 2 * NN; task += nwaves) {
        int d = deg[task];
        int m = min(d, CAP);
        int idx = 0;
        if (lane < m) idx = bins[(size_t)task * CAP + lane];
        float a00=0.f,a01=0.f, a10=0.f,a11=0.f, a20=0.f,a21=0.f, a30=0.f,a31=0.f;
        int F = m >> 1;                // complete pair-steps
        int q = 0;
        for (; q + 4 <= F; q += 4) {
            int s0 = __shfl(idx, 2*(q+0) + half);
            int s1 = __shfl(idx, 2*(q+1) + half);
            int s2 = __shfl(idx, 2*(q+2) + half);
            int s3 = __shfl(idx, 2*(q+3) + half);
            unsigned u0 = hb32[(size_t)s0 * 32 + p];
            unsigned u1 = hb32[(size_t)s1 * 32 + p];
            unsigned u2 = hb32[(size_t)s2 * 32 + p];
            unsigned u3 = hb32[(size_t)s3 * 32 + p];
            a00 += __uint_as_float(u0 << 16); a01 += __uint_as_float(u0 & 0xffff0000u);
            a10 += __uint_as_float(u1 << 16); a11 += __uint_as_float(u1 & 0xffff0000u);
            a20 += __uint_as_float(u2 << 16); a21 += __uint_as_float(u2 & 0xffff0000u);
            a30 += __uint_as_float(u3 << 16); a31 += __uint_as_float(u3 & 0xffff0000u);
        }
        for (; q < F; ++q) {
            int s = __shfl(idx, 2*q + half);
            unsigned u = hb32[(size_t)s * 32 + p];
            a00 += __uint_as_float(u << 16); a01 += __uint_as_float(u & 0xffff0000u);
        }
        if (m & 1) {
            int s = __shfl(idx, m - 1);
            if (half == 0) {
                unsigned u = hb32[(size_t)s * 32 + p];
                a00 += __uint_as_float(u << 16); a01 += __uint_as_float(u & 0xffff0000u);
            }
        }
        float s0 = (a00 + a10) + (a20 + a30);
        float s1 = (a01 + a11) + (a21 + a31);
        s0 += __shfl_xor(s0, 32);
        s1 += __shfl_xor(s1, 32);
        if (half == 0) {
            float inv = 1.0f / (float)max(d, 1);
            *(float2*)&agg[(size_t)task * 64 + 2 * p] = make_float2(s0 * inv, s1 * inv);
        }
    }
}

// Overflow fixup on fp32 h (tiny work; agg stays fp32 so atomicAdd works).
__global__ __launch_bounds__(256) void ovf_fix(
    const int2* __restrict__ ovf, const int* __restrict__ ovf_cnt,
    const int* __restrict__ deg, const float* __restrict__ h,
    float* __restrict__ agg)
{
    int cnt = min(*ovf_cnt, OVF_CAP);
    int total = cnt * 64;
    int stride = gridDim.x * blockDim.x;
    for (int t = blockIdx.x * blockDim.x + threadIdx.x; t < total; t += stride) {
        int e = t >> 6, f = t & 63;
        int2 v = ovf[e];
        float val = h[(size_t)v.y * 64 + f] / (float)max(deg[v.x], 1);
        atomicAdd(&agg[(size_t)v.x * 64 + f], val);
    }
}

// hout = relu(mean0@Wl0 + mean1@Wl1 + self@(Wr0+Wr1) + (b0+b1))
#define RST 132
__global__ __launch_bounds__(256) void layer_gemm(
    const float* __restrict__ agg0, const float* __restrict__ agg1,
    const unsigned short* __restrict__ selfb,
    const float* __restrict__ Wl0, const float* __restrict__ Wl1,
    const float* __restrict__ Wr0, const float* __restrict__ Wr1,
    const float* __restrict__ b0, const float* __restrict__ b1,
    float* __restrict__ hout, unsigned short* __restrict__ hb16)
{
    __shared__ float Wch[64 * 64];
    __shared__ float rowsT[64 * RST];
    __shared__ float bias[64];

    int tid = threadIdx.x;
    int base = blockIdx.x * 128;
    if (tid < 64) bias[tid] = b0[tid] + b1[tid];

    int j8 = (tid & 7) * 8;
    int n4 = (tid >> 3) * 4;

    float acc[4][8];
    #pragma unroll
    for (int i = 0; i < 4; i++)
        #pragma unroll
        for (int c = 0; c < 8; c++) acc[i][c] = 0.f;

    for (int chunk = 0; chunk < 3; chunk++) {
        const float* W = (chunk == 0) ? Wl0 : (chunk == 1) ? Wl1 : Wr0;
        __syncthreads();
        #pragma unroll
        for (int r = 0; r < 4; r++) {
            int i = tid + 256 * r;
            float4 w = *(const float4*)&W[i * 4];
            if (chunk == 2) {
                float4 w2 = *(const float4*)&Wr1[i * 4];
                w.x += w2.x; w.y += w2.y; w.z += w2.z; w.w += w2.w;
            }
            *(float4*)&Wch[i * 4] = w;
        }
        if (chunk < 2) {
            const float* src = (chunk == 0) ? agg0 : agg1;
            #pragma unroll
            for (int r = 0; r < 8; r++) {
                int i = tid + 256 * r;
                int node = i >> 4;
                int k4 = (i & 15) * 4;
                float4 v = make_float4(0.f, 0.f, 0.f, 0.f);
                int g = base + node;
                if (g < NN) v = *(const float4*)&src[(size_t)g * 64 + k4];
                rowsT[(k4 + 0) * RST + node] = v.x;
                rowsT[(k4 + 1) * RST + node] = v.y;
                rowsT[(k4 + 2) * RST + node] = v.z;
                rowsT[(k4 + 3) * RST + node] = v.w;
            }
        } else {
            #pragma unroll
            for (int r = 0; r < 8; r++) {
                int i = tid + 256 * r;
                int node = i >> 4;
                int k4 = (i & 15) * 4;
                int g = base + node;
                ushort4 u = make_ushort4(0, 0, 0, 0);
                if (g < NN) u = *(const ushort4*)&selfb[(size_t)g * 64 + k4];
                rowsT[(k4 + 0) * RST + node] = bf2f(u.x);
                rowsT[(k4 + 1) * RST + node] = bf2f(u.y);
                rowsT[(k4 + 2) * RST + node] = bf2f(u.z);
                rowsT[(k4 + 3) * RST + node] = bf2f(u.w);
            }
        }
        __syncthreads();
        #pragma unroll 4
        for (int k = 0; k < 64; k++) {
            float4 wa = *(const float4*)&Wch[k * 64 + j8];
            float4 wb = *(const float4*)&Wch[k * 64 + j8 + 4];
            float4 rv = *(const float4*)&rowsT[k * RST + n4];
            float w[8] = {wa.x, wa.y, wa.z, wa.w, wb.x, wb.y, wb.z, wb.w};
            float rr[4] = {rv.x, rv.y, rv.z, rv.w};
            #pragma unroll
            for (int i = 0; i < 4; i++)
                #pragma unroll
                for (int c = 0; c < 8; c++)
                    acc[i][c] = fmaf(rr[i], w[c], acc[i][c]);
        }
    }

    #pragma unroll
    for (int i = 0; i < 4; i++) {
        int g = base + n4 + i;
        if (g < NN) {
            float4 o1, o2;
            o1.x = fmaxf(acc[i][0] + bias[j8 + 0], 0.f);
            o1.y = fmaxf(acc[i][1] + bias[j8 + 1], 0.f);
            o1.z = fmaxf(acc[i][2] + bias[j8 + 2], 0.f);
            o1.w = fmaxf(acc[i][3] + bias[j8 + 3], 0.f);
            o2.x = fmaxf(acc[i][4] + bias[j8 + 4], 0.f);
            o2.y = fmaxf(acc[i][5] + bias[j8 + 5], 0.f);
            o2.z = fmaxf(acc[i][6] + bias[j8 + 6], 0.f);
            o2.w = fmaxf(acc[i][7] + bias[j8 + 7], 0.f);
            *(float4*)&hout[(size_t)g * 64 + j8]     = o1;
            *(float4*)&hout[(size_t)g * 64 + j8 + 4] = o2;
            if (hb16) {
                ushort4 p0, p1;
                p0.x = f2bf(o1.x); p0.y = f2bf(o1.y); p0.z = f2bf(o1.z); p0.w = f2bf(o1.w);
                p1.x = f2bf(o2.x); p1.y = f2bf(o2.y); p1.z = f2bf(o2.z); p1.w = f2bf(o2.w);
                *(ushort4*)&hb16[(size_t)g * 64 + j8]     = p0;
                *(ushort4*)&hb16[(size_t)g * 64 + j8 + 4] = p1;
            }
        }
    }
}

// out[i,:32] = h[i,:64] @ W + b
__global__ __launch_bounds__(256) void final_gemm(
    const float* __restrict__ h, const float* __restrict__ W,
    const float* __restrict__ b, float* __restrict__ out)
{
    __shared__ float Ws[64 * 32];
    __shared__ float bs[32];
    __shared__ float rows[8][64];

    int tid = threadIdx.x;
    for (int i = tid; i < 2048; i += 256) Ws[i] = W[i];
    if (tid < 32) bs[tid] = b[tid];

    int j = tid & 31;
    int nl = tid >> 5;

    for (int base = blockIdx.x * 8; base < NN; base += gridDim.x * 8) {
        __syncthreads();
        if (tid < 128) {
            int n = tid >> 4, kq = tid & 15;
            int node = base + n;
            float4 v = make_float4(0.f, 0.f, 0.f, 0.f);
            if (node < NN) v = *(const float4*)&h[(size_t)node * 64 + kq * 4];
            *(float4*)&rows[n][kq * 4] = v;
        }
        __syncthreads();

        int node = base + nl;
        if (node < NN) {
            float acc = bs[j];
            #pragma unroll
            for (int k = 0; k < 64; k += 4) {
                float4 rv = *(const float4*)&rows[nl][k];
                acc = fmaf(rv.x, Ws[(k + 0) * 32 + j], acc);
                acc = fmaf(rv.y, Ws[(k + 1) * 32 + j], acc);
                acc = fmaf(rv.z, Ws[(k + 2) * 32 + j], acc);
                acc = fmaf(rv.w, Ws[(k + 3) * 32 + j], acc);
            }
            out[(size_t)node * 32 + j] = acc;
        }
    }
}

extern "C" void kernel_launch(void* const* d_in, const int* in_sizes, int n_in,
                              void* d_out, int out_size, void* d_ws, size_t ws_size,
                              hipStream_t stream)
{
    const float* x    = (const float*)d_in[0];
    const int*   ei0  = (const int*)d_in[1];
    const int*   ei1  = (const int*)d_in[2];
    const float* Wl   = (const float*)d_in[3];   // [2,2,64,64]
    const float* Wr   = (const float*)d_in[4];   // [2,2,64,64]
    const float* bl   = (const float*)d_in[5];   // [2,2,64]
    const float* linW = (const float*)d_in[6];   // [64,32]
    const float* linb = (const float*)d_in[7];   // [32]
    float* out = (float*)d_out;

    int E0 = in_sizes[1] / 2;
    int E1 = in_sizes[2] / 2;

    // Workspace (large, aligned buffers first):
    // [bins 6.4MB us | agg 25.6MB f | h1 12.8MB f | xb 6.4MB us | h1b 6.4MB us |
    //  deg 400KB | ovf_cnt(8) | bcnt(NB) | ovf]  ~58 MB
    // bbuf (phase A<->B bucket storage, 8.4MB) ALIASES agg: agg is dead until
    // aggregate runs, which is after bin_build.
    unsigned short* bins = (unsigned short*)d_ws;
    float* agg  = (float*)(bins + (size_t)2 * NN * CAP);
    float* agg0 = agg;
    float* agg1 = agg + (size_t)NN * 64;
    float* h1   = agg + (size_t)2 * NN * 64;
    unsigned short* xb  = (unsigned short*)(h1 + (size_t)NN * 64);
    unsigned short* h1b = xb + (size_t)NN * 64;
    int*  deg     = (int*)(h1b + (size_t)NN * 64);
    int*  ovf_cnt = deg + 2 * NN;
    int*  bcnt    = ovf_cnt + 8;
    int2* ovf     = (int2*)(bcnt + NB);
    unsigned int* bbuf = (unsigned int*)agg;     // aliased

    dim3 blk(256);
    int ggrid = (NN + 127) / 128;   // 391

    (void)hipMemsetAsync(ovf_cnt, 0, (8 + NB) * sizeof(int), stream);
    bucket_scatter<<<512, blk, 0, stream>>>(ei0, E0, ei1, E1, bbuf, bcnt);
    bin_build<<<NB, dim3(1024), 0, stream>>>(bbuf, bcnt, deg, bins, ovf, ovf_cnt);
    to_bf16<<<1024, blk, 0, stream>>>(x, xb, NN * 16);

    // ---- Layer 0 (gather from xb, self from xb) ----
    aggregate<<<4096, blk, 0, stream>>>(bins, deg, xb, agg);
    ovf_fix<<<64, blk, 0, stream>>>(ovf, ovf_cnt, deg, x, agg);
    layer_gemm<<<ggrid, blk, 0, stream>>>(agg0, agg1, xb,
        Wl + 0, Wl + 4096, Wr + 0, Wr + 4096, bl + 0, bl + 64, h1, h1b);

    // ---- Layer 1 (gather from h1b, self from h1b, hout in h1) ----
    aggregate<<<4096, blk, 0, stream>>>(bins, deg, h1b, agg);
    ovf_fix<<<64, blk, 0, stream>>>(ovf, ovf_cnt, deg, h1, agg);
    layer_gemm<<<ggrid, blk, 0, stream>>>(agg0, agg1, h1b,
        Wl + 8192, Wl + 12288, Wr + 8192, Wr + 12288, bl + 128, bl + 192, h1, (unsigned short*)nullptr);

    // ---- Final projection ----
    final_gemm<<<768, blk, 0, stream>>>(h1, linW, linb, out);
}

// Round 12
// 295.142 us; speedup vs baseline: 2.6780x; 2.6780x over previous
//
#include <hip/hip_runtime.h>

#define NN 50000
#define CAP 32          // per-node bin capacity; overflow handled correctly
#define OVF_CAP 4096
#define SHARD_W 12500   // 4 contiguous node ranges per relation

__device__ __forceinline__ unsigned short f2bf(float f) {
    unsigned u = __float_as_uint(f);
    u += 0x7fffu + ((u >> 16) & 1u);           // round-to-nearest-even
    return (unsigned short)(u >> 16);
}
__device__ __forceinline__ float bf2f(unsigned short u) {
    return __uint_as_float(((unsigned)u) << 16);
}

// fp32 -> bf16 row copy (n4 = count of float4s)
__global__ __launch_bounds__(256) void to_bf16(
    const float* __restrict__ in, unsigned short* __restrict__ out, int n4)
{
    int stride = gridDim.x * blockDim.x;
    for (int i = blockIdx.x * blockDim.x + threadIdx.x; i < n4; i += stride) {
        float4 v = ((const float4*)in)[i];
        ushort4 o;
        o.x = f2bf(v.x); o.y = f2bf(v.y); o.z = f2bf(v.z); o.w = f2bf(v.w);
        ((ushort4*)out)[i] = o;
    }
}

// Range-sharded single-pass bin fill (R7/R10 structure — best measured 72us).
// Groups 0-3 scan ei0, own node range [g*12500,(g+1)*12500); groups 4-7 ei1.
// Scattered-atomic plateau ~1.25 TB/s is empirically insensitive to sharding/
// NT/alignment/LDS-staging alternatives (R4-R11) — this is the wall-clock
// optimum found for this op shape.
__global__ __launch_bounds__(256) void bin_fill(
    const int* __restrict__ ei0, int E0,
    const int* __restrict__ ei1, int E1,
    int* __restrict__ deg, unsigned short* __restrict__ bins,
    int2* __restrict__ ovf, int* __restrict__ ovf_cnt)
{
    int grp  = blockIdx.x & 7;
    int lblk = blockIdx.x >> 3;
    int lgrid = gridDim.x >> 3;
    const int* ei; int E; int baseT;
    if (grp < 4) { ei = ei0; E = E0; baseT = 0; }
    else         { ei = ei1; E = E1; baseT = NN; }
    int want = grp & 3;

    int stride = lgrid * blockDim.x;
    for (int t = lblk * blockDim.x + threadIdx.x; t < E; t += stride) {
        int dstv = ei[E + t];
        if (dstv / SHARD_W == want) {
            int task = baseT + dstv;
            int s = ei[t];
            int r = atomicAdd(&deg[task], 1);
            if (r < CAP) {
                bins[(size_t)task * CAP + r] = (unsigned short)s;
            } else {
                int o = atomicAdd(ovf_cnt, 1);
                if (o < OVF_CAP) ovf[o] = make_int2(task, s);
            }
        }
    }
}

// One (rel,node) task per wave; paired gathers: lane loads a uint (2 bf16
// feats), low half-wave covers src 2q, high half src 2q+1 -> 2 rows per
// gather instruction at 4B/lane. 4 chains of ILP. ~1.9 lines/cyc/XCD =
// near L2 request-rate bound (each edge needs one 128B row request).
__global__ __launch_bounds__(256) void aggregate(
    const unsigned short* __restrict__ bins, const int* __restrict__ deg,
    const unsigned short* __restrict__ hb, float* __restrict__ agg)
{
    int lane = threadIdx.x & 63;
    int half = lane >> 5;
    int p = lane & 31;                 // feature-pair index
    int wid = (blockIdx.x * blockDim.x + threadIdx.x) >> 6;
    int nwaves = (gridDim.x * blockDim.x) >> 6;
    const unsigned int* hb32 = (const unsigned int*)hb;

    for (int task = wid; task < 2 * NN; task += nwaves) {
        int d = deg[task];
        int m = min(d, CAP);
        int idx = 0;
        if (lane < m) idx = bins[(size_t)task * CAP + lane];
        float a00=0.f,a01=0.f, a10=0.f,a11=0.f, a20=0.f,a21=0.f, a30=0.f,a31=0.f;
        int F = m >> 1;                // complete pair-steps
        int q = 0;
        for (; q + 4 <= F; q += 4) {
            int s0 = __shfl(idx, 2*(q+0) + half);
            int s1 = __shfl(idx, 2*(q+1) + half);
            int s2 = __shfl(idx, 2*(q+2) + half);
            int s3 = __shfl(idx, 2*(q+3) + half);
            unsigned u0 = hb32[(size_t)s0 * 32 + p];
            unsigned u1 = hb32[(size_t)s1 * 32 + p];
            unsigned u2 = hb32[(size_t)s2 * 32 + p];
            unsigned u3 = hb32[(size_t)s3 * 32 + p];
            a00 += __uint_as_float(u0 << 16); a01 += __uint_as_float(u0 & 0xffff0000u);
            a10 += __uint_as_float(u1 << 16); a11 += __uint_as_float(u1 & 0xffff0000u);
            a20 += __uint_as_float(u2 << 16); a21 += __uint_as_float(u2 & 0xffff0000u);
            a30 += __uint_as_float(u3 << 16); a31 += __uint_as_float(u3 & 0xffff0000u);
        }
        for (; q < F; ++q) {
            int s = __shfl(idx, 2*q + half);
            unsigned u = hb32[(size_t)s * 32 + p];
            a00 += __uint_as_float(u << 16); a01 += __uint_as_float(u & 0xffff0000u);
        }
        if (m & 1) {
            int s = __shfl(idx, m - 1);
            if (half == 0) {
                unsigned u = hb32[(size_t)s * 32 + p];
                a00 += __uint_as_float(u << 16); a01 += __uint_as_float(u & 0xffff0000u);
            }
        }
        float s0 = (a00 + a10) + (a20 + a30);
        float s1 = (a01 + a11) + (a21 + a31);
        s0 += __shfl_xor(s0, 32);
        s1 += __shfl_xor(s1, 32);
        if (half == 0) {
            float inv = 1.0f / (float)max(d, 1);
            *(float2*)&agg[(size_t)task * 64 + 2 * p] = make_float2(s0 * inv, s1 * inv);
        }
    }
}

// Overflow fixup on fp32 h (tiny work; agg stays fp32 so atomicAdd works).
__global__ __launch_bounds__(256) void ovf_fix(
    const int2* __restrict__ ovf, const int* __restrict__ ovf_cnt,
    const int* __restrict__ deg, const float* __restrict__ h,
    float* __restrict__ agg)
{
    int cnt = min(*ovf_cnt, OVF_CAP);
    int total = cnt * 64;
    int stride = gridDim.x * blockDim.x;
    for (int t = blockIdx.x * blockDim.x + threadIdx.x; t < total; t += stride) {
        int e = t >> 6, f = t & 63;
        int2 v = ovf[e];
        float val = h[(size_t)v.y * 64 + f] / (float)max(deg[v.x], 1);
        atomicAdd(&agg[(size_t)v.x * 64 + f], val);
    }
}

// hout = relu(mean0@Wl0 + mean1@Wl1 + self@(Wr0+Wr1) + (b0+b1))
#define RST 132
__global__ __launch_bounds__(256) void layer_gemm(
    const float* __restrict__ agg0, const float* __restrict__ agg1,
    const unsigned short* __restrict__ selfb,
    const float* __restrict__ Wl0, const float* __restrict__ Wl1,
    const float* __restrict__ Wr0, const float* __restrict__ Wr1,
    const float* __restrict__ b0, const float* __restrict__ b1,
    float* __restrict__ hout, unsigned short* __restrict__ hb16)
{
    __shared__ float Wch[64 * 64];
    __shared__ float rowsT[64 * RST];
    __shared__ float bias[64];

    int tid = threadIdx.x;
    int base = blockIdx.x * 128;
    if (tid < 64) bias[tid] = b0[tid] + b1[tid];

    int j8 = (tid & 7) * 8;
    int n4 = (tid >> 3) * 4;

    float acc[4][8];
    #pragma unroll
    for (int i = 0; i < 4; i++)
        #pragma unroll
        for (int c = 0; c < 8; c++) acc[i][c] = 0.f;

    for (int chunk = 0; chunk < 3; chunk++) {
        const float* W = (chunk == 0) ? Wl0 : (chunk == 1) ? Wl1 : Wr0;
        __syncthreads();
        #pragma unroll
        for (int r = 0; r < 4; r++) {
            int i = tid + 256 * r;
            float4 w = *(const float4*)&W[i * 4];
            if (chunk == 2) {
                float4 w2 = *(const float4*)&Wr1[i * 4];
                w.x += w2.x; w.y += w2.y; w.z += w2.z; w.w += w2.w;
            }
            *(float4*)&Wch[i * 4] = w;
        }
        if (chunk < 2) {
            const float* src = (chunk == 0) ? agg0 : agg1;
            #pragma unroll
            for (int r = 0; r < 8; r++) {
                int i = tid + 256 * r;
                int node = i >> 4;
                int k4 = (i & 15) * 4;
                float4 v = make_float4(0.f, 0.f, 0.f, 0.f);
                int g = base + node;
                if (g < NN) v = *(const float4*)&src[(size_t)g * 64 + k4];
                rowsT[(k4 + 0) * RST + node] = v.x;
                rowsT[(k4 + 1) * RST + node] = v.y;
                rowsT[(k4 + 2) * RST + node] = v.z;
                rowsT[(k4 + 3) * RST + node] = v.w;
            }
        } else {
            #pragma unroll
            for (int r = 0; r < 8; r++) {
                int i = tid + 256 * r;
                int node = i >> 4;
                int k4 = (i & 15) * 4;
                int g = base + node;
                ushort4 u = make_ushort4(0, 0, 0, 0);
                if (g < NN) u = *(const ushort4*)&selfb[(size_t)g * 64 + k4];
                rowsT[(k4 + 0) * RST + node] = bf2f(u.x);
                rowsT[(k4 + 1) * RST + node] = bf2f(u.y);
                rowsT[(k4 + 2) * RST + node] = bf2f(u.z);
                rowsT[(k4 + 3) * RST + node] = bf2f(u.w);
            }
        }
        __syncthreads();
        #pragma unroll 4
        for (int k = 0; k < 64; k++) {
            float4 wa = *(const float4*)&Wch[k * 64 + j8];
            float4 wb = *(const float4*)&Wch[k * 64 + j8 + 4];
            float4 rv = *(const float4*)&rowsT[k * RST + n4];
            float w[8] = {wa.x, wa.y, wa.z, wa.w, wb.x, wb.y, wb.z, wb.w};
            float rr[4] = {rv.x, rv.y, rv.z, rv.w};
            #pragma unroll
            for (int i = 0; i < 4; i++)
                #pragma unroll
                for (int c = 0; c < 8; c++)
                    acc[i][c] = fmaf(rr[i], w[c], acc[i][c]);
        }
    }

    #pragma unroll
    for (int i = 0; i < 4; i++) {
        int g = base + n4 + i;
        if (g < NN) {
            float4 o1, o2;
            o1.x = fmaxf(acc[i][0] + bias[j8 + 0], 0.f);
            o1.y = fmaxf(acc[i][1] + bias[j8 + 1], 0.f);
            o1.z = fmaxf(acc[i][2] + bias[j8 + 2], 0.f);
            o1.w = fmaxf(acc[i][3] + bias[j8 + 3], 0.f);
            o2.x = fmaxf(acc[i][4] + bias[j8 + 4], 0.f);
            o2.y = fmaxf(acc[i][5] + bias[j8 + 5], 0.f);
            o2.z = fmaxf(acc[i][6] + bias[j8 + 6], 0.f);
            o2.w = fmaxf(acc[i][7] + bias[j8 + 7], 0.f);
            *(float4*)&hout[(size_t)g * 64 + j8]     = o1;
            *(float4*)&hout[(size_t)g * 64 + j8 + 4] = o2;
            if (hb16) {
                ushort4 p0, p1;
                p0.x = f2bf(o1.x); p0.y = f2bf(o1.y); p0.z = f2bf(o1.z); p0.w = f2bf(o1.w);
                p1.x = f2bf(o2.x); p1.y = f2bf(o2.y); p1.z = f2bf(o2.z); p1.w = f2bf(o2.w);
                *(ushort4*)&hb16[(size_t)g * 64 + j8]     = p0;
                *(ushort4*)&hb16[(size_t)g * 64 + j8 + 4] = p1;
            }
        }
    }
}

// out[i,:32] = h[i,:64] @ W + b
__global__ __launch_bounds__(256) void final_gemm(
    const float* __restrict__ h, const float* __restrict__ W,
    const float* __restrict__ b, float* __restrict__ out)
{
    __shared__ float Ws[64 * 32];
    __shared__ float bs[32];
    __shared__ float rows[8][64];

    int tid = threadIdx.x;
    for (int i = tid; i < 2048; i += 256) Ws[i] = W[i];
    if (tid < 32) bs[tid] = b[tid];

    int j = tid & 31;
    int nl = tid >> 5;

    for (int base = blockIdx.x * 8; base < NN; base += gridDim.x * 8) {
        __syncthreads();
        if (tid < 128) {
            int n = tid >> 4, kq = tid & 15;
            int node = base + n;
            float4 v = make_float4(0.f, 0.f, 0.f, 0.f);
            if (node < NN) v = *(const float4*)&h[(size_t)node * 64 + kq * 4];
            *(float4*)&rows[n][kq * 4] = v;
        }
        __syncthreads();

        int node = base + nl;
        if (node < NN) {
            float acc = bs[j];
            #pragma unroll
            for (int k = 0; k < 64; k += 4) {
                float4 rv = *(const float4*)&rows[nl][k];
                acc = fmaf(rv.x, Ws[(k + 0) * 32 + j], acc);
                acc = fmaf(rv.y, Ws[(k + 1) * 32 + j], acc);
                acc = fmaf(rv.z, Ws[(k + 2) * 32 + j], acc);
                acc = fmaf(rv.w, Ws[(k + 3) * 32 + j], acc);
            }
            out[(size_t)node * 32 + j] = acc;
        }
    }
}

extern "C" void kernel_launch(void* const* d_in, const int* in_sizes, int n_in,
                              void* d_out, int out_size, void* d_ws, size_t ws_size,
                              hipStream_t stream)
{
    const float* x    = (const float*)d_in[0];
    const int*   ei0  = (const int*)d_in[1];
    const int*   ei1  = (const int*)d_in[2];
    const float* Wl   = (const float*)d_in[3];   // [2,2,64,64]
    const float* Wr   = (const float*)d_in[4];   // [2,2,64,64]
    const float* bl   = (const float*)d_in[5];   // [2,2,64]
    const float* linW = (const float*)d_in[6];   // [64,32]
    const float* linb = (const float*)d_in[7];   // [32]
    float* out = (float*)d_out;

    int E0 = in_sizes[1] / 2;
    int E1 = in_sizes[2] / 2;

    // Workspace (large, aligned buffers first):
    // [bins 6.4MB us | agg 25.6MB f | h1 12.8MB f | xb 6.4MB us | h1b 6.4MB us |
    //  deg 400KB | ovf_cnt(pad) | ovf]  ~58 MB
    unsigned short* bins = (unsigned short*)d_ws;
    float* agg  = (float*)(bins + (size_t)2 * NN * CAP);
    float* agg0 = agg;
    float* agg1 = agg + (size_t)NN * 64;
    float* h1   = agg + (size_t)2 * NN * 64;
    unsigned short* xb  = (unsigned short*)(h1 + (size_t)NN * 64);
    unsigned short* h1b = xb + (size_t)NN * 64;
    int*  deg     = (int*)(h1b + (size_t)NN * 64);
    int*  ovf_cnt = deg + 2 * NN;
    int2* ovf     = (int2*)(ovf_cnt + 8);

    dim3 blk(256);
    int ggrid = (NN + 127) / 128;   // 391

    (void)hipMemsetAsync(deg, 0, (2 * NN + 8) * sizeof(int), stream);
    bin_fill<<<2048, blk, 0, stream>>>(ei0, E0, ei1, E1, deg, bins, ovf, ovf_cnt);
    to_bf16<<<1024, blk, 0, stream>>>(x, xb, NN * 16);

    // ---- Layer 0 (gather from xb, self from xb) ----
    aggregate<<<4096, blk, 0, stream>>>(bins, deg, xb, agg);
    ovf_fix<<<64, blk, 0, stream>>>(ovf, ovf_cnt, deg, x, agg);
    layer_gemm<<<ggrid, blk, 0, stream>>>(agg0, agg1, xb,
        Wl + 0, Wl + 4096, Wr + 0, Wr + 4096, bl + 0, bl + 64, h1, h1b);

    // ---- Layer 1 (gather from h1b, self from h1b, hout in h1) ----
    aggregate<<<4096, blk, 0, stream>>>(bins, deg, h1b, agg);
    ovf_fix<<<64, blk, 0, stream>>>(ovf, ovf_cnt, deg, h1, agg);
    layer_gemm<<<ggrid, blk, 0, stream>>>(agg0, agg1, h1b,
        Wl + 8192, Wl + 12288, Wr + 8192, Wr + 12288, bl + 128, bl + 192, h1, (unsigned short*)nullptr);

    // ---- Final projection ----
    final_gemm<<<768, blk, 0, stream>>>(h1, linW, linb, out);
}

// Round 13
// 281.441 us; speedup vs baseline: 2.8084x; 1.0487x over previous
//
#include <hip/hip_runtime.h>

#define NN 50000
#define CAP 32          // per-node bin capacity; overflow handled correctly
#define OVF_CAP 4096
#define SHARD_W 12500   // 4 contiguous node ranges per relation

__device__ __forceinline__ unsigned short f2bf(float f) {
    unsigned u = __float_as_uint(f);
    u += 0x7fffu + ((u >> 16) & 1u);           // round-to-nearest-even
    return (unsigned short)(u >> 16);
}
__device__ __forceinline__ float bf2f(unsigned short u) {
    return __uint_as_float(((unsigned)u) << 16);
}

// Fused init: zero deg+ovf_cnt AND convert x -> bf16 (was 2 dispatches).
__global__ __launch_bounds__(256) void init_fuse(
    const float* __restrict__ in, unsigned short* __restrict__ out, int n4,
    int* __restrict__ deg, int nint)
{
    int stride = gridDim.x * blockDim.x;
    int id0 = blockIdx.x * blockDim.x + threadIdx.x;
    for (int i = id0; i < n4; i += stride) {
        float4 v = ((const float4*)in)[i];
        ushort4 o;
        o.x = f2bf(v.x); o.y = f2bf(v.y); o.z = f2bf(v.z); o.w = f2bf(v.w);
        ((ushort4*)out)[i] = o;
    }
    for (int i = id0; i < nint; i += stride) deg[i] = 0;
}

// Range-sharded single-pass bin fill (R7/R10 structure — best measured 72us).
// Groups 0-3 scan ei0, own node range [g*12500,(g+1)*12500); groups 4-7 ei1.
// Scattered-atomic plateau ~1.25 TB/s is empirically insensitive to sharding/
// NT/alignment/LDS-staging alternatives (R4-R11).
__global__ __launch_bounds__(256) void bin_fill(
    const int* __restrict__ ei0, int E0,
    const int* __restrict__ ei1, int E1,
    int* __restrict__ deg, unsigned short* __restrict__ bins,
    int2* __restrict__ ovf, int* __restrict__ ovf_cnt)
{
    int grp  = blockIdx.x & 7;
    int lblk = blockIdx.x >> 3;
    int lgrid = gridDim.x >> 3;
    const int* ei; int E; int baseT;
    if (grp < 4) { ei = ei0; E = E0; baseT = 0; }
    else         { ei = ei1; E = E1; baseT = NN; }
    int want = grp & 3;

    int stride = lgrid * blockDim.x;
    for (int t = lblk * blockDim.x + threadIdx.x; t < E; t += stride) {
        int dstv = ei[E + t];
        if (dstv / SHARD_W == want) {
            int task = baseT + dstv;
            int s = ei[t];
            int r = atomicAdd(&deg[task], 1);
            if (r < CAP) {
                bins[(size_t)task * CAP + r] = (unsigned short)s;
            } else {
                int o = atomicAdd(ovf_cnt, 1);
                if (o < OVF_CAP) ovf[o] = make_int2(task, s);
            }
        }
    }
}

// One (rel,node) task per wave; paired bf16 gathers (R9/R10 form).
// NEW: waves whose task overflowed (d > CAP) scan the tiny ovf list inline
// (wave-uniform match) — removes the separate ovf_fix dispatches.
__global__ __launch_bounds__(256) void aggregate(
    const unsigned short* __restrict__ bins, const int* __restrict__ deg,
    const unsigned short* __restrict__ hb, float* __restrict__ agg,
    const int2* __restrict__ ovf, const int* __restrict__ ovf_cnt)
{
    int lane = threadIdx.x & 63;
    int half = lane >> 5;
    int p = lane & 31;                 // feature-pair index
    int wid = (blockIdx.x * blockDim.x + threadIdx.x) >> 6;
    int nwaves = (gridDim.x * blockDim.x) >> 6;
    const unsigned int* hb32 = (const unsigned int*)hb;

    for (int task = wid; task < 2 * NN; task += nwaves) {
        int d = deg[task];
        int m = min(d, CAP);
        int idx = 0;
        if (lane < m) idx = bins[(size_t)task * CAP + lane];
        float a00=0.f,a01=0.f, a10=0.f,a11=0.f, a20=0.f,a21=0.f, a30=0.f,a31=0.f;
        int F = m >> 1;                // complete pair-steps
        int q = 0;
        for (; q + 4 <= F; q += 4) {
            int s0 = __shfl(idx, 2*(q+0) + half);
            int s1 = __shfl(idx, 2*(q+1) + half);
            int s2 = __shfl(idx, 2*(q+2) + half);
            int s3 = __shfl(idx, 2*(q+3) + half);
            unsigned u0 = hb32[(size_t)s0 * 32 + p];
            unsigned u1 = hb32[(size_t)s1 * 32 + p];
            unsigned u2 = hb32[(size_t)s2 * 32 + p];
            unsigned u3 = hb32[(size_t)s3 * 32 + p];
            a00 += __uint_as_float(u0 << 16); a01 += __uint_as_float(u0 & 0xffff0000u);
            a10 += __uint_as_float(u1 << 16); a11 += __uint_as_float(u1 & 0xffff0000u);
            a20 += __uint_as_float(u2 << 16); a21 += __uint_as_float(u2 & 0xffff0000u);
            a30 += __uint_as_float(u3 << 16); a31 += __uint_as_float(u3 & 0xffff0000u);
        }
        for (; q < F; ++q) {
            int s = __shfl(idx, 2*q + half);
            unsigned u = hb32[(size_t)s * 32 + p];
            a00 += __uint_as_float(u << 16); a01 += __uint_as_float(u & 0xffff0000u);
        }
        if (m & 1) {
            int s = __shfl(idx, m - 1);
            if (half == 0) {
                unsigned u = hb32[(size_t)s * 32 + p];
                a00 += __uint_as_float(u << 16); a01 += __uint_as_float(u & 0xffff0000u);
            }
        }
        if (d > CAP) {                 // rare: pick up this task's overflow edges
            int cnt = min(*ovf_cnt, OVF_CAP);
            for (int e = 0; e < cnt; ++e) {
                int2 v = ovf[e];
                if (v.x == task && half == 0) {
                    unsigned u = hb32[(size_t)v.y * 32 + p];
                    a00 += __uint_as_float(u << 16); a01 += __uint_as_float(u & 0xffff0000u);
                }
            }
        }
        float s0 = (a00 + a10) + (a20 + a30);
        float s1 = (a01 + a11) + (a21 + a31);
        s0 += __shfl_xor(s0, 32);
        s1 += __shfl_xor(s1, 32);
        if (half == 0) {
            float inv = 1.0f / (float)max(d, 1);
            *(float2*)&agg[(size_t)task * 64 + 2 * p] = make_float2(s0 * inv, s1 * inv);
        }
    }
}

// L0: hout = relu(mean0@Wl0 + mean1@Wl1 + self@(Wr0+Wr1) + (b0+b1)),
// fp32 + bf16 mirror outputs.
#define RST 132
__global__ __launch_bounds__(256) void layer_gemm(
    const float* __restrict__ agg0, const float* __restrict__ agg1,
    const unsigned short* __restrict__ selfb,
    const float* __restrict__ Wl0, const float* __restrict__ Wl1,
    const float* __restrict__ Wr0, const float* __restrict__ Wr1,
    const float* __restrict__ b0, const float* __restrict__ b1,
    float* __restrict__ hout, unsigned short* __restrict__ hb16)
{
    __shared__ float Wch[64 * 64];
    __shared__ float rowsT[64 * RST];
    __shared__ float bias[64];

    int tid = threadIdx.x;
    int base = blockIdx.x * 128;
    if (tid < 64) bias[tid] = b0[tid] + b1[tid];

    int j8 = (tid & 7) * 8;
    int n4 = (tid >> 3) * 4;

    float acc[4][8];
    #pragma unroll
    for (int i = 0; i < 4; i++)
        #pragma unroll
        for (int c = 0; c < 8; c++) acc[i][c] = 0.f;

    for (int chunk = 0; chunk < 3; chunk++) {
        const float* W = (chunk == 0) ? Wl0 : (chunk == 1) ? Wl1 : Wr0;
        __syncthreads();
        #pragma unroll
        for (int r = 0; r < 4; r++) {
            int i = tid + 256 * r;
            float4 w = *(const float4*)&W[i * 4];
            if (chunk == 2) {
                float4 w2 = *(const float4*)&Wr1[i * 4];
                w.x += w2.x; w.y += w2.y; w.z += w2.z; w.w += w2.w;
            }
            *(float4*)&Wch[i * 4] = w;
        }
        if (chunk < 2) {
            const float* src = (chunk == 0) ? agg0 : agg1;
            #pragma unroll
            for (int r = 0; r < 8; r++) {
                int i = tid + 256 * r;
                int node = i >> 4;
                int k4 = (i & 15) * 4;
                float4 v = make_float4(0.f, 0.f, 0.f, 0.f);
                int g = base + node;
                if (g < NN) v = *(const float4*)&src[(size_t)g * 64 + k4];
                rowsT[(k4 + 0) * RST + node] = v.x;
                rowsT[(k4 + 1) * RST + node] = v.y;
                rowsT[(k4 + 2) * RST + node] = v.z;
                rowsT[(k4 + 3) * RST + node] = v.w;
            }
        } else {
            #pragma unroll
            for (int r = 0; r < 8; r++) {
                int i = tid + 256 * r;
                int node = i >> 4;
                int k4 = (i & 15) * 4;
                int g = base + node;
                ushort4 u = make_ushort4(0, 0, 0, 0);
                if (g < NN) u = *(const ushort4*)&selfb[(size_t)g * 64 + k4];
                rowsT[(k4 + 0) * RST + node] = bf2f(u.x);
                rowsT[(k4 + 1) * RST + node] = bf2f(u.y);
                rowsT[(k4 + 2) * RST + node] = bf2f(u.z);
                rowsT[(k4 + 3) * RST + node] = bf2f(u.w);
            }
        }
        __syncthreads();
        #pragma unroll 4
        for (int k = 0; k < 64; k++) {
            float4 wa = *(const float4*)&Wch[k * 64 + j8];
            float4 wb = *(const float4*)&Wch[k * 64 + j8 + 4];
            float4 rv = *(const float4*)&rowsT[k * RST + n4];
            float w[8] = {wa.x, wa.y, wa.z, wa.w, wb.x, wb.y, wb.z, wb.w};
            float rr[4] = {rv.x, rv.y, rv.z, rv.w};
            #pragma unroll
            for (int i = 0; i < 4; i++)
                #pragma unroll
                for (int c = 0; c < 8; c++)
                    acc[i][c] = fmaf(rr[i], w[c], acc[i][c]);
        }
    }

    #pragma unroll
    for (int i = 0; i < 4; i++) {
        int g = base + n4 + i;
        if (g < NN) {
            float4 o1, o2;
            o1.x = fmaxf(acc[i][0] + bias[j8 + 0], 0.f);
            o1.y = fmaxf(acc[i][1] + bias[j8 + 1], 0.f);
            o1.z = fmaxf(acc[i][2] + bias[j8 + 2], 0.f);
            o1.w = fmaxf(acc[i][3] + bias[j8 + 3], 0.f);
            o2.x = fmaxf(acc[i][4] + bias[j8 + 4], 0.f);
            o2.y = fmaxf(acc[i][5] + bias[j8 + 5], 0.f);
            o2.z = fmaxf(acc[i][6] + bias[j8 + 6], 0.f);
            o2.w = fmaxf(acc[i][7] + bias[j8 + 7], 0.f);
            *(float4*)&hout[(size_t)g * 64 + j8]     = o1;
            *(float4*)&hout[(size_t)g * 64 + j8 + 4] = o2;
            ushort4 p0, p1;
            p0.x = f2bf(o1.x); p0.y = f2bf(o1.y); p0.z = f2bf(o1.z); p0.w = f2bf(o1.w);
            p1.x = f2bf(o2.x); p1.y = f2bf(o2.y); p1.z = f2bf(o2.z); p1.w = f2bf(o2.w);
            *(ushort4*)&hb16[(size_t)g * 64 + j8]     = p0;
            *(ushort4*)&hb16[(size_t)g * 64 + j8 + 4] = p1;
        }
    }
}

// L1 + final fused: h2 = relu(mean0@Wl0 + mean1@Wl1 + self@(Wr0+Wr1) + b),
// then out = h2 @ linW + linb — h2 tile stays in LDS, never hits HBM.
__global__ __launch_bounds__(256) void layer_gemm_final(
    const float* __restrict__ agg0, const float* __restrict__ agg1,
    const unsigned short* __restrict__ selfb,
    const float* __restrict__ Wl0, const float* __restrict__ Wl1,
    const float* __restrict__ Wr0, const float* __restrict__ Wr1,
    const float* __restrict__ b0, const float* __restrict__ b1,
    const float* __restrict__ linW, const float* __restrict__ linb,
    float* __restrict__ out)
{
    __shared__ float Wch[64 * 64];
    __shared__ float rowsT[64 * RST];
    __shared__ float bias[64];

    int tid = threadIdx.x;
    int base = blockIdx.x * 128;
    if (tid < 64) bias[tid] = b0[tid] + b1[tid];

    int j8 = (tid & 7) * 8;
    int n4 = (tid >> 3) * 4;

    float acc[4][8];
    #pragma unroll
    for (int i = 0; i < 4; i++)
        #pragma unroll
        for (int c = 0; c < 8; c++) acc[i][c] = 0.f;

    for (int chunk = 0; chunk < 3; chunk++) {
        const float* W = (chunk == 0) ? Wl0 : (chunk == 1) ? Wl1 : Wr0;
        __syncthreads();
        #pragma unroll
        for (int r = 0; r < 4; r++) {
            int i = tid + 256 * r;
            float4 w = *(const float4*)&W[i * 4];
            if (chunk == 2) {
                float4 w2 = *(const float4*)&Wr1[i * 4];
                w.x += w2.x; w.y += w2.y; w.z += w2.z; w.w += w2.w;
            }
            *(float4*)&Wch[i * 4] = w;
        }
        if (chunk < 2) {
            const float* src = (chunk == 0) ? agg0 : agg1;
            #pragma unroll
            for (int r = 0; r < 8; r++) {
                int i = tid + 256 * r;
                int node = i >> 4;
                int k4 = (i & 15) * 4;
                float4 v = make_float4(0.f, 0.f, 0.f, 0.f);
                int g = base + node;
                if (g < NN) v = *(const float4*)&src[(size_t)g * 64 + k4];
                rowsT[(k4 + 0) * RST + node] = v.x;
                rowsT[(k4 + 1) * RST + node] = v.y;
                rowsT[(k4 + 2) * RST + node] = v.z;
                rowsT[(k4 + 3) * RST + node] = v.w;
            }
        } else {
            #pragma unroll
            for (int r = 0; r < 8; r++) {
                int i = tid + 256 * r;
                int node = i >> 4;
                int k4 = (i & 15) * 4;
                int g = base + node;
                ushort4 u = make_ushort4(0, 0, 0, 0);
                if (g < NN) u = *(const ushort4*)&selfb[(size_t)g * 64 + k4];
                rowsT[(k4 + 0) * RST + node] = bf2f(u.x);
                rowsT[(k4 + 1) * RST + node] = bf2f(u.y);
                rowsT[(k4 + 2) * RST + node] = bf2f(u.z);
                rowsT[(k4 + 3) * RST + node] = bf2f(u.w);
            }
        }
        __syncthreads();
        #pragma unroll 4
        for (int k = 0; k < 64; k++) {
            float4 wa = *(const float4*)&Wch[k * 64 + j8];
            float4 wb = *(const float4*)&Wch[k * 64 + j8 + 4];
            float4 rv = *(const float4*)&rowsT[k * RST + n4];
            float w[8] = {wa.x, wa.y, wa.z, wa.w, wb.x, wb.y, wb.z, wb.w};
            float rr[4] = {rv.x, rv.y, rv.z, rv.w};
            #pragma unroll
            for (int i = 0; i < 4; i++)
                #pragma unroll
                for (int c = 0; c < 8; c++)
                    acc[i][c] = fmaf(rr[i], w[c], acc[i][c]);
        }
    }

    // relu epilogue into registers
    float o[4][8];
    #pragma unroll
    for (int i = 0; i < 4; i++)
        #pragma unroll
        for (int c = 0; c < 8; c++)
            o[i][c] = fmaxf(acc[i][c] + bias[j8 + c], 0.f);

    __syncthreads();   // everyone done reading Wch/rowsT/bias

    // restage: Wch <- linW (64x32), bias <- linb, rowsT <- h2 tile transposed
    #pragma unroll
    for (int r = 0; r < 2; r++) {
        int i = tid + 256 * r;   // 512 float4 = 2048 floats
        *(float4*)&Wch[i * 4] = *(const float4*)&linW[i * 4];
    }
    if (tid < 32) bias[tid] = linb[tid];
    #pragma unroll
    for (int i = 0; i < 4; i++)
        #pragma unroll
        for (int c = 0; c < 8; c++)
            rowsT[(j8 + c) * RST + (n4 + i)] = o[i][c];
    __syncthreads();

    // mini-GEMM: out[128 x 32] = h2_tile @ linW + linb
    int j4 = (tid & 7) * 4;
    float acc2[4][4];
    #pragma unroll
    for (int i = 0; i < 4; i++)
        #pragma unroll
        for (int c = 0; c < 4; c++) acc2[i][c] = 0.f;
    #pragma unroll 4
    for (int k = 0; k < 64; k++) {
        float4 w = *(const float4*)&Wch[k * 32 + j4];
        float4 rv = *(const float4*)&rowsT[k * RST + n4];
        float wr[4] = {w.x, w.y, w.z, w.w};
        float rr[4] = {rv.x, rv.y, rv.z, rv.w};
        #pragma unroll
        for (int i = 0; i < 4; i++)
            #pragma unroll
            for (int c = 0; c < 4; c++)
                acc2[i][c] = fmaf(rr[i], wr[c], acc2[i][c]);
    }
    #pragma unroll
    for (int i = 0; i < 4; i++) {
        int g = base + n4 + i;
        if (g < NN) {
            float4 ov;
            ov.x = acc2[i][0] + bias[j4 + 0];
            ov.y = acc2[i][1] + bias[j4 + 1];
            ov.z = acc2[i][2] + bias[j4 + 2];
            ov.w = acc2[i][3] + bias[j4 + 3];
            *(float4*)&out[(size_t)g * 32 + j4] = ov;
        }
    }
}

extern "C" void kernel_launch(void* const* d_in, const int* in_sizes, int n_in,
                              void* d_out, int out_size, void* d_ws, size_t ws_size,
                              hipStream_t stream)
{
    const float* x    = (const float*)d_in[0];
    const int*   ei0  = (const int*)d_in[1];
    const int*   ei1  = (const int*)d_in[2];
    const float* Wl   = (const float*)d_in[3];   // [2,2,64,64]
    const float* Wr   = (const float*)d_in[4];   // [2,2,64,64]
    const float* bl   = (const float*)d_in[5];   // [2,2,64]
    const float* linW = (const float*)d_in[6];   // [64,32]
    const float* linb = (const float*)d_in[7];   // [32]
    float* out = (float*)d_out;

    int E0 = in_sizes[1] / 2;
    int E1 = in_sizes[2] / 2;

    // Workspace (large, aligned buffers first):
    // [bins 6.4MB us | agg 25.6MB f | h1 12.8MB f | xb 6.4MB us | h1b 6.4MB us |
    //  deg 400KB | ovf_cnt(pad) | ovf]  ~58 MB
    unsigned short* bins = (unsigned short*)d_ws;
    float* agg  = (float*)(bins + (size_t)2 * NN * CAP);
    float* agg0 = agg;
    float* agg1 = agg + (size_t)NN * 64;
    float* h1   = agg + (size_t)2 * NN * 64;
    unsigned short* xb  = (unsigned short*)(h1 + (size_t)NN * 64);
    unsigned short* h1b = xb + (size_t)NN * 64;
    int*  deg     = (int*)(h1b + (size_t)NN * 64);
    int*  ovf_cnt = deg + 2 * NN;
    int2* ovf     = (int2*)(ovf_cnt + 8);

    dim3 blk(256);
    int ggrid = (NN + 127) / 128;   // 391

    init_fuse<<<1024, blk, 0, stream>>>(x, xb, NN * 16, deg, 2 * NN + 8);
    bin_fill<<<2048, blk, 0, stream>>>(ei0, E0, ei1, E1, deg, bins, ovf, ovf_cnt);

    // ---- Layer 0 (gather from xb, self from xb; h1 fp32 + h1b bf16 out) ----
    aggregate<<<4096, blk, 0, stream>>>(bins, deg, xb, agg, ovf, ovf_cnt);
    layer_gemm<<<ggrid, blk, 0, stream>>>(agg0, agg1, xb,
        Wl + 0, Wl + 4096, Wr + 0, Wr + 4096, bl + 0, bl + 64, h1, h1b);

    // ---- Layer 1 + final projection fused (h2 never materialized) ----
    aggregate<<<4096, blk, 0, stream>>>(bins, deg, h1b, agg, ovf, ovf_cnt);
    layer_gemm_final<<<ggrid, blk, 0, stream>>>(agg0, agg1, h1b,
        Wl + 8192, Wl + 12288, Wr + 8192, Wr + 12288, bl + 128, bl + 192,
        linW, linb, out);
}

// Round 14
// 278.982 us; speedup vs baseline: 2.8332x; 1.0088x over previous
//
#include <hip/hip_runtime.h>

#define NN 50000
#define CAP 32          // per-node bin capacity; overflow handled correctly
#define OVF_CAP 4096
#define SHARD_W 12500   // 4 contiguous node ranges per relation

__device__ __forceinline__ unsigned short f2bf(float f) {
    unsigned u = __float_as_uint(f);
    u += 0x7fffu + ((u >> 16) & 1u);           // round-to-nearest-even
    return (unsigned short)(u >> 16);
}
__device__ __forceinline__ float bf2f(unsigned short u) {
    return __uint_as_float(((unsigned)u) << 16);
}

// Fused init: zero deg+ovf_cnt AND convert x -> bf16.
__global__ __launch_bounds__(256) void init_fuse(
    const float* __restrict__ in, unsigned short* __restrict__ out, int n4,
    int* __restrict__ deg, int nint)
{
    int stride = gridDim.x * blockDim.x;
    int id0 = blockIdx.x * blockDim.x + threadIdx.x;
    for (int i = id0; i < n4; i += stride) {
        float4 v = ((const float4*)in)[i];
        ushort4 o;
        o.x = f2bf(v.x); o.y = f2bf(v.y); o.z = f2bf(v.z); o.w = f2bf(v.w);
        ((ushort4*)out)[i] = o;
    }
    for (int i = id0; i < nint; i += stride) deg[i] = 0;
}

// Range-sharded single-pass bin fill (R7/R10 — measured plateau 71us;
// scattered-atomic wall is insensitive to sharding/NT/alignment/LDS-staging,
// R4-R11).
__global__ __launch_bounds__(256) void bin_fill(
    const int* __restrict__ ei0, int E0,
    const int* __restrict__ ei1, int E1,
    int* __restrict__ deg, unsigned short* __restrict__ bins,
    int2* __restrict__ ovf, int* __restrict__ ovf_cnt)
{
    int grp  = blockIdx.x & 7;
    int lblk = blockIdx.x >> 3;
    int lgrid = gridDim.x >> 3;
    const int* ei; int E; int baseT;
    if (grp < 4) { ei = ei0; E = E0; baseT = 0; }
    else         { ei = ei1; E = E1; baseT = NN; }
    int want = grp & 3;

    int stride = lgrid * blockDim.x;
    for (int t = lblk * blockDim.x + threadIdx.x; t < E; t += stride) {
        int dstv = ei[E + t];
        if (dstv / SHARD_W == want) {
            int task = baseT + dstv;
            int s = ei[t];
            int r = atomicAdd(&deg[task], 1);
            if (r < CAP) {
                bins[(size_t)task * CAP + r] = (unsigned short)s;
            } else {
                int o = atomicAdd(ovf_cnt, 1);
                if (o < OVF_CAP) ovf[o] = make_int2(task, s);
            }
        }
    }
}

// One (rel,node) task per wave; paired bf16 gathers; inline overflow pickup.
// NEW: mean written in bf16 (one uint per lane) — halves agg traffic; agg is
// consumed exactly once by the GEMM, which reads bf16 anyway for self path.
__global__ __launch_bounds__(256) void aggregate(
    const unsigned short* __restrict__ bins, const int* __restrict__ deg,
    const unsigned short* __restrict__ hb, unsigned short* __restrict__ agg,
    const int2* __restrict__ ovf, const int* __restrict__ ovf_cnt)
{
    int lane = threadIdx.x & 63;
    int half = lane >> 5;
    int p = lane & 31;                 // feature-pair index
    int wid = (blockIdx.x * blockDim.x + threadIdx.x) >> 6;
    int nwaves = (gridDim.x * blockDim.x) >> 6;
    const unsigned int* hb32 = (const unsigned int*)hb;
    unsigned int* agg32 = (unsigned int*)agg;

    for (int task = wid; task < 2 * NN; task += nwaves) {
        int d = deg[task];
        int m = min(d, CAP);
        int idx = 0;
        if (lane < m) idx = bins[(size_t)task * CAP + lane];
        float a00=0.f,a01=0.f, a10=0.f,a11=0.f, a20=0.f,a21=0.f, a30=0.f,a31=0.f;
        int F = m >> 1;                // complete pair-steps
        int q = 0;
        for (; q + 4 <= F; q += 4) {
            int s0 = __shfl(idx, 2*(q+0) + half);
            int s1 = __shfl(idx, 2*(q+1) + half);
            int s2 = __shfl(idx, 2*(q+2) + half);
            int s3 = __shfl(idx, 2*(q+3) + half);
            unsigned u0 = hb32[(size_t)s0 * 32 + p];
            unsigned u1 = hb32[(size_t)s1 * 32 + p];
            unsigned u2 = hb32[(size_t)s2 * 32 + p];
            unsigned u3 = hb32[(size_t)s3 * 32 + p];
            a00 += __uint_as_float(u0 << 16); a01 += __uint_as_float(u0 & 0xffff0000u);
            a10 += __uint_as_float(u1 << 16); a11 += __uint_as_float(u1 & 0xffff0000u);
            a20 += __uint_as_float(u2 << 16); a21 += __uint_as_float(u2 & 0xffff0000u);
            a30 += __uint_as_float(u3 << 16); a31 += __uint_as_float(u3 & 0xffff0000u);
        }
        for (; q < F; ++q) {
            int s = __shfl(idx, 2*q + half);
            unsigned u = hb32[(size_t)s * 32 + p];
            a00 += __uint_as_float(u << 16); a01 += __uint_as_float(u & 0xffff0000u);
        }
        if (m & 1) {
            int s = __shfl(idx, m - 1);
            if (half == 0) {
                unsigned u = hb32[(size_t)s * 32 + p];
                a00 += __uint_as_float(u << 16); a01 += __uint_as_float(u & 0xffff0000u);
            }
        }
        if (d > CAP) {                 // rare: pick up this task's overflow edges
            int cnt = min(*ovf_cnt, OVF_CAP);
            for (int e = 0; e < cnt; ++e) {
                int2 v = ovf[e];
                if (v.x == task && half == 0) {
                    unsigned u = hb32[(size_t)v.y * 32 + p];
                    a00 += __uint_as_float(u << 16); a01 += __uint_as_float(u & 0xffff0000u);
                }
            }
        }
        float s0 = (a00 + a10) + (a20 + a30);
        float s1 = (a01 + a11) + (a21 + a31);
        s0 += __shfl_xor(s0, 32);
        s1 += __shfl_xor(s1, 32);
        if (half == 0) {
            float inv = 1.0f / (float)max(d, 1);
            unsigned lo = (unsigned)f2bf(s0 * inv);
            unsigned hi = (unsigned)f2bf(s1 * inv);
            agg32[(size_t)task * 32 + p] = lo | (hi << 16);
        }
    }
}

// L0: h1b = bf16( relu(mean0@Wl0 + mean1@Wl1 + self@(Wr0+Wr1) + b) ).
// All three K-chunks staged from bf16 sources. fp32 h1 is dead — removed.
#define RST 132
__global__ __launch_bounds__(256) void layer_gemm(
    const unsigned short* __restrict__ agg0, const unsigned short* __restrict__ agg1,
    const unsigned short* __restrict__ selfb,
    const float* __restrict__ Wl0, const float* __restrict__ Wl1,
    const float* __restrict__ Wr0, const float* __restrict__ Wr1,
    const float* __restrict__ b0, const float* __restrict__ b1,
    unsigned short* __restrict__ hb16)
{
    __shared__ float Wch[64 * 64];
    __shared__ float rowsT[64 * RST];
    __shared__ float bias[64];

    int tid = threadIdx.x;
    int base = blockIdx.x * 128;
    if (tid < 64) bias[tid] = b0[tid] + b1[tid];

    int j8 = (tid & 7) * 8;
    int n4 = (tid >> 3) * 4;

    float acc[4][8];
    #pragma unroll
    for (int i = 0; i < 4; i++)
        #pragma unroll
        for (int c = 0; c < 8; c++) acc[i][c] = 0.f;

    for (int chunk = 0; chunk < 3; chunk++) {
        const float* W = (chunk == 0) ? Wl0 : (chunk == 1) ? Wl1 : Wr0;
        const unsigned short* src = (chunk == 0) ? agg0 : (chunk == 1) ? agg1 : selfb;
        __syncthreads();
        #pragma unroll
        for (int r = 0; r < 4; r++) {
            int i = tid + 256 * r;
            float4 w = *(const float4*)&W[i * 4];
            if (chunk == 2) {
                float4 w2 = *(const float4*)&Wr1[i * 4];
                w.x += w2.x; w.y += w2.y; w.z += w2.z; w.w += w2.w;
            }
            *(float4*)&Wch[i * 4] = w;
        }
        #pragma unroll
        for (int r = 0; r < 8; r++) {
            int i = tid + 256 * r;
            int node = i >> 4;
            int k4 = (i & 15) * 4;
            int g = base + node;
            ushort4 u = make_ushort4(0, 0, 0, 0);
            if (g < NN) u = *(const ushort4*)&src[(size_t)g * 64 + k4];
            rowsT[(k4 + 0) * RST + node] = bf2f(u.x);
            rowsT[(k4 + 1) * RST + node] = bf2f(u.y);
            rowsT[(k4 + 2) * RST + node] = bf2f(u.z);
            rowsT[(k4 + 3) * RST + node] = bf2f(u.w);
        }
        __syncthreads();
        #pragma unroll 4
        for (int k = 0; k < 64; k++) {
            float4 wa = *(const float4*)&Wch[k * 64 + j8];
            float4 wb = *(const float4*)&Wch[k * 64 + j8 + 4];
            float4 rv = *(const float4*)&rowsT[k * RST + n4];
            float w[8] = {wa.x, wa.y, wa.z, wa.w, wb.x, wb.y, wb.z, wb.w};
            float rr[4] = {rv.x, rv.y, rv.z, rv.w};
            #pragma unroll
            for (int i = 0; i < 4; i++)
                #pragma unroll
                for (int c = 0; c < 8; c++)
                    acc[i][c] = fmaf(rr[i], w[c], acc[i][c]);
        }
    }

    #pragma unroll
    for (int i = 0; i < 4; i++) {
        int g = base + n4 + i;
        if (g < NN) {
            ushort4 p0, p1;
            p0.x = f2bf(fmaxf(acc[i][0] + bias[j8 + 0], 0.f));
            p0.y = f2bf(fmaxf(acc[i][1] + bias[j8 + 1], 0.f));
            p0.z = f2bf(fmaxf(acc[i][2] + bias[j8 + 2], 0.f));
            p0.w = f2bf(fmaxf(acc[i][3] + bias[j8 + 3], 0.f));
            p1.x = f2bf(fmaxf(acc[i][4] + bias[j8 + 4], 0.f));
            p1.y = f2bf(fmaxf(acc[i][5] + bias[j8 + 5], 0.f));
            p1.z = f2bf(fmaxf(acc[i][6] + bias[j8 + 6], 0.f));
            p1.w = f2bf(fmaxf(acc[i][7] + bias[j8 + 7], 0.f));
            *(ushort4*)&hb16[(size_t)g * 64 + j8]     = p0;
            *(ushort4*)&hb16[(size_t)g * 64 + j8 + 4] = p1;
        }
    }
}

// L1 + final fused: h2 tile in LDS, then out = h2 @ linW + linb.
__global__ __launch_bounds__(256) void layer_gemm_final(
    const unsigned short* __restrict__ agg0, const unsigned short* __restrict__ agg1,
    const unsigned short* __restrict__ selfb,
    const float* __restrict__ Wl0, const float* __restrict__ Wl1,
    const float* __restrict__ Wr0, const float* __restrict__ Wr1,
    const float* __restrict__ b0, const float* __restrict__ b1,
    const float* __restrict__ linW, const float* __restrict__ linb,
    float* __restrict__ out)
{
    __shared__ float Wch[64 * 64];
    __shared__ float rowsT[64 * RST];
    __shared__ float bias[64];

    int tid = threadIdx.x;
    int base = blockIdx.x * 128;
    if (tid < 64) bias[tid] = b0[tid] + b1[tid];

    int j8 = (tid & 7) * 8;
    int n4 = (tid >> 3) * 4;

    float acc[4][8];
    #pragma unroll
    for (int i = 0; i < 4; i++)
        #pragma unroll
        for (int c = 0; c < 8; c++) acc[i][c] = 0.f;

    for (int chunk = 0; chunk < 3; chunk++) {
        const float* W = (chunk == 0) ? Wl0 : (chunk == 1) ? Wl1 : Wr0;
        const unsigned short* src = (chunk == 0) ? agg0 : (chunk == 1) ? agg1 : selfb;
        __syncthreads();
        #pragma unroll
        for (int r = 0; r < 4; r++) {
            int i = tid + 256 * r;
            float4 w = *(const float4*)&W[i * 4];
            if (chunk == 2) {
                float4 w2 = *(const float4*)&Wr1[i * 4];
                w.x += w2.x; w.y += w2.y; w.z += w2.z; w.w += w2.w;
            }
            *(float4*)&Wch[i * 4] = w;
        }
        #pragma unroll
        for (int r = 0; r < 8; r++) {
            int i = tid + 256 * r;
            int node = i >> 4;
            int k4 = (i & 15) * 4;
            int g = base + node;
            ushort4 u = make_ushort4(0, 0, 0, 0);
            if (g < NN) u = *(const ushort4*)&src[(size_t)g * 64 + k4];
            rowsT[(k4 + 0) * RST + node] = bf2f(u.x);
            rowsT[(k4 + 1) * RST + node] = bf2f(u.y);
            rowsT[(k4 + 2) * RST + node] = bf2f(u.z);
            rowsT[(k4 + 3) * RST + node] = bf2f(u.w);
        }
        __syncthreads();
        #pragma unroll 4
        for (int k = 0; k < 64; k++) {
            float4 wa = *(const float4*)&Wch[k * 64 + j8];
            float4 wb = *(const float4*)&Wch[k * 64 + j8 + 4];
            float4 rv = *(const float4*)&rowsT[k * RST + n4];
            float w[8] = {wa.x, wa.y, wa.z, wa.w, wb.x, wb.y, wb.z, wb.w};
            float rr[4] = {rv.x, rv.y, rv.z, rv.w};
            #pragma unroll
            for (int i = 0; i < 4; i++)
                #pragma unroll
                for (int c = 0; c < 8; c++)
                    acc[i][c] = fmaf(rr[i], w[c], acc[i][c]);
        }
    }

    // relu epilogue into registers
    float o[4][8];
    #pragma unroll
    for (int i = 0; i < 4; i++)
        #pragma unroll
        for (int c = 0; c < 8; c++)
            o[i][c] = fmaxf(acc[i][c] + bias[j8 + c], 0.f);

    __syncthreads();   // everyone done reading Wch/rowsT/bias

    // restage: Wch <- linW (64x32), bias <- linb, rowsT <- h2 tile transposed
    #pragma unroll
    for (int r = 0; r < 2; r++) {
        int i = tid + 256 * r;   // 512 float4 = 2048 floats
        *(float4*)&Wch[i * 4] = *(const float4*)&linW[i * 4];
    }
    if (tid < 32) bias[tid] = linb[tid];
    #pragma unroll
    for (int i = 0; i < 4; i++)
        #pragma unroll
        for (int c = 0; c < 8; c++)
            rowsT[(j8 + c) * RST + (n4 + i)] = o[i][c];
    __syncthreads();

    // mini-GEMM: out[128 x 32] = h2_tile @ linW + linb
    int j4 = (tid & 7) * 4;
    float acc2[4][4];
    #pragma unroll
    for (int i = 0; i < 4; i++)
        #pragma unroll
        for (int c = 0; c < 4; c++) acc2[i][c] = 0.f;
    #pragma unroll 4
    for (int k = 0; k < 64; k++) {
        float4 w = *(const float4*)&Wch[k * 32 + j4];
        float4 rv = *(const float4*)&rowsT[k * RST + n4];
        float wr[4] = {w.x, w.y, w.z, w.w};
        float rr[4] = {rv.x, rv.y, rv.z, rv.w};
        #pragma unroll
        for (int i = 0; i < 4; i++)
            #pragma unroll
            for (int c = 0; c < 4; c++)
                acc2[i][c] = fmaf(rr[i], wr[c], acc2[i][c]);
    }
    #pragma unroll
    for (int i = 0; i < 4; i++) {
        int g = base + n4 + i;
        if (g < NN) {
            float4 ov;
            ov.x = acc2[i][0] + bias[j4 + 0];
            ov.y = acc2[i][1] + bias[j4 + 1];
            ov.z = acc2[i][2] + bias[j4 + 2];
            ov.w = acc2[i][3] + bias[j4 + 3];
            *(float4*)&out[(size_t)g * 32 + j4] = ov;
        }
    }
}

extern "C" void kernel_launch(void* const* d_in, const int* in_sizes, int n_in,
                              void* d_out, int out_size, void* d_ws, size_t ws_size,
                              hipStream_t stream)
{
    const float* x    = (const float*)d_in[0];
    const int*   ei0  = (const int*)d_in[1];
    const int*   ei1  = (const int*)d_in[2];
    const float* Wl   = (const float*)d_in[3];   // [2,2,64,64]
    const float* Wr   = (const float*)d_in[4];   // [2,2,64,64]
    const float* bl   = (const float*)d_in[5];   // [2,2,64]
    const float* linW = (const float*)d_in[6];   // [64,32]
    const float* linb = (const float*)d_in[7];   // [32]
    float* out = (float*)d_out;

    int E0 = in_sizes[1] / 2;
    int E1 = in_sizes[2] / 2;

    // Workspace (large, aligned buffers first; all bf16 intermediates now):
    // [bins 6.4MB | aggb 12.8MB | xb 6.4MB | h1b 6.4MB | deg 400KB | ovf]  ~32.5MB
    unsigned short* bins = (unsigned short*)d_ws;
    unsigned short* aggb = bins + (size_t)2 * NN * CAP;
    unsigned short* agg0 = aggb;
    unsigned short* agg1 = aggb + (size_t)NN * 64;
    unsigned short* xb   = aggb + (size_t)2 * NN * 64;
    unsigned short* h1b  = xb + (size_t)NN * 64;
    int*  deg     = (int*)(h1b + (size_t)NN * 64);
    int*  ovf_cnt = deg + 2 * NN;
    int2* ovf     = (int2*)(ovf_cnt + 8);

    dim3 blk(256);
    int ggrid = (NN + 127) / 128;   // 391

    init_fuse<<<1024, blk, 0, stream>>>(x, xb, NN * 16, deg, 2 * NN + 8);
    bin_fill<<<2048, blk, 0, stream>>>(ei0, E0, ei1, E1, deg, bins, ovf, ovf_cnt);

    // ---- Layer 0 (gather + self from xb; h1b bf16 out) ----
    aggregate<<<4096, blk, 0, stream>>>(bins, deg, xb, aggb, ovf, ovf_cnt);
    layer_gemm<<<ggrid, blk, 0, stream>>>(agg0, agg1, xb,
        Wl + 0, Wl + 4096, Wr + 0, Wr + 4096, bl + 0, bl + 64, h1b);

    // ---- Layer 1 + final projection fused (h2 never materialized) ----
    aggregate<<<4096, blk, 0, stream>>>(bins, deg, h1b, aggb, ovf, ovf_cnt);
    layer_gemm_final<<<ggrid, blk, 0, stream>>>(agg0, agg1, h1b,
        Wl + 8192, Wl + 12288, Wr + 8192, Wr + 12288, bl + 128, bl + 192,
        linW, linb, out);
}